// Round 4
// baseline (532.145 us; speedup 1.0000x reference)
//
#include <hip/hip_runtime.h>
#include <hip/hip_bf16.h>

// Problem constants
#define NCHUNK 32
#define NBATCH 64
#define HALF   128
#define SIZE   (2 * HALF)          // 256
#define NROWS  (NCHUNK * NBATCH)   // 2048
#define C_SCALE 1e-4f
#define M_SCALE 1e-5f

#define JB_F4    16384             // float4 elements per J copy (256 KB)
#define JBLOCKS  NROWS             // one block per J copy, contiguous stream
#define YBLOCKS  (NROWS * HALF / 256)  // 1024 blocks for ydot

// native clang vector type — __builtin_nontemporal_store accepts this
typedef float floatx4 __attribute__((ext_vector_type(4)));

// ---------------------------------------------------------------------------
// Fused kernel.
//  Blocks [0, 2048): J. Block b streams copy b CONTIGUOUSLY (256 KB), exactly
//    like a memset: step st writes float4 range [st*256, st*256+255] (4 KB).
//    Per-thread column base c0 = (tid&63)*4 is FIXED; row r = st*4 + wave_id
//    is wave-uniform, so the tridiagonal scalars are recomputed per step from
//    a handful of broadcast loads (~20 VALU/step, hidden under stores).
//    Nontemporal stores: final output, no reuse -> skip L2 allocate.
//  Blocks [2048, 3072): ydot. gid -> (row, i), same math as before.
// ---------------------------------------------------------------------------
__global__ __launch_bounds__(256) void fused_kernel(
        const float* __restrict__ t,
        const float* __restrict__ y,
        const float* __restrict__ K,
        const float* __restrict__ C,
        const float* __restrict__ M,
        float* __restrict__ out) {
    int b   = blockIdx.x;
    int tid = threadIdx.x;

    if (b < JBLOCKS) {
        floatx4* dst = (floatx4*)(out + (long)NROWS * SIZE) + (long)b * JB_F4;
        int w  = __builtin_amdgcn_readfirstlane(tid >> 6);  // wave id 0..3
        int c0 = (tid & 63) << 2;                           // fixed col base
        bool  isV = (c0 >= HALF);
        int   j0  = isV ? (c0 - HALF) : c0;
        float scl = isV ? C_SCALE : 1.0f;
        const float* __restrict__ A = isV ? C : K;

        #pragma unroll
        for (int st = 0; st < 64; ++st) {
            int r = (st << 2) + w;          // wave-uniform row
            floatx4 val;
            if (r < HALF) {
                // top half: [0 | I] -> 1 at col = r + HALF
                int d = r + HALF - c0;      // matching k
                val.x = (d == 0) ? 1.0f : 0.0f;
                val.y = (d == 1) ? 1.0f : 0.0f;
                val.z = (d == 2) ? 1.0f : 0.0f;
                val.w = (d == 3) ? 1.0f : 0.0f;
            } else {
                int   i    = r - HALF;
                float invM = 1.0f / (M[i] * M_SCALE);
                float Ai   = A[i] * scl;
                float Aim  = (i > 0) ? A[i - 1] * scl : 0.0f;
                float diag = -(Ai + Aim) * invM;            // col j == i
                float sup  = (i < HALF - 1) ? Ai * invM : 0.0f;  // col j == i+1
                float sub  = Aim * invM;                    // col j == i-1
                int d = i - j0;   // k==d -> diag, k==d+1 -> sup, k==d-1 -> sub
                val.x = (d == 0) ? diag : (d == -1) ? sup : (d == 1) ? sub : 0.0f;
                val.y = (d == 1) ? diag : (d ==  0) ? sup : (d == 2) ? sub : 0.0f;
                val.z = (d == 2) ? diag : (d ==  1) ? sup : (d == 3) ? sub : 0.0f;
                val.w = (d == 3) ? diag : (d ==  2) ? sup : (d == 4) ? sub : 0.0f;
            }
            __builtin_nontemporal_store(val, dst + st * 256 + tid);
        }
    } else {
        // ---- ydot ----
        int gid = (b - JBLOCKS) * 256 + tid;   // 0 .. 2048*128-1
        int row = gid >> 7;                    // 0..2047
        int i   = gid & 127;                   // 0..127
        const float* yr = y + (long)row * SIZE;

        float u = yr[i];
        float v = yr[HALF + i];
        out[(long)row * SIZE + i] = v;

        float Mi   = M[i] * M_SCALE;
        float vdot = 0.0f;
        if (i < HALF - 1) {
            float f = K[i] * (yr[i + 1] - u) + C[i] * C_SCALE * (yr[HALF + i + 1] - v);
            vdot += f / Mi;
        }
        if (i >= 1) {
            float fm = K[i - 1] * (u - yr[i - 1]) + C[i - 1] * C_SCALE * (v - yr[HALF + i - 1]);
            vdot -= fm / Mi;
        }
        if (i == HALF - 1) {
            vdot += -(K[HALF - 1] * u + C[HALF - 1] * C_SCALE * v) / Mi;
        }
        if (i == 0) {
            vdot += sinf(t[row]) / Mi;
        }
        out[(long)row * SIZE + HALF + i] = vdot;
    }
}

extern "C" void kernel_launch(void* const* d_in, const int* in_sizes, int n_in,
                              void* d_out, int out_size, void* d_ws, size_t ws_size,
                              hipStream_t stream) {
    const float* t = (const float*)d_in[0];   // (32,64)
    const float* y = (const float*)d_in[1];   // (32,64,256)
    const float* K = (const float*)d_in[2];   // (128,)
    const float* C = (const float*)d_in[3];   // (128,)
    const float* M = (const float*)d_in[4];   // (128,)

    float* out = (float*)d_out;

    fused_kernel<<<JBLOCKS + YBLOCKS, 256, 0, stream>>>(t, y, K, C, M, out);
}